// Round 9
// baseline (209.811 us; speedup 1.0000x reference)
//
#include <hip/hip_runtime.h>

#define B_  2
#define S_  2048
#define D_  1024
#define H_  16
#define HD_ 64
#define M_  4096   // B_*S_

typedef __attribute__((ext_vector_type(8))) short  short8;
typedef __attribute__((ext_vector_type(4))) float  floatx4;

__device__ __forceinline__ unsigned short f2bf(float f) {
  unsigned int u = __float_as_uint(f);
  u = (u + 0x7fffu + ((u >> 16) & 1u)) >> 16;   // RNE
  return (unsigned short)u;
}

// async global->LDS, 16B per lane; lds dest = wave-uniform base + lane*16
__device__ __forceinline__ void gl_lds16(const short* g, short* l) {
  __builtin_amdgcn_global_load_lds(
      (const __attribute__((address_space(1))) unsigned int*)g,
      (__attribute__((address_space(3))) unsigned int*)l, 16, 0, 0);
}

// ---------------------------------------------------------------- cast fp32->bf16
__global__ __launch_bounds__(256) void cast_kernel(
    const float* __restrict__ x,  const float* __restrict__ wq,
    const float* __restrict__ wk, const float* __restrict__ wv,
    const float* __restrict__ wo,
    short* __restrict__ xb,  short* __restrict__ wqb, short* __restrict__ wkb,
    short* __restrict__ wvb, short* __restrict__ wob) {
  const float* src; short* dst; int n8;
  switch (blockIdx.y) {
    case 0:  src = x;  dst = xb;  n8 = (M_ * D_) / 8; break;
    case 1:  src = wq; dst = wqb; n8 = (D_ * D_) / 8; break;
    case 2:  src = wk; dst = wkb; n8 = (D_ * D_) / 8; break;
    case 3:  src = wv; dst = wvb; n8 = (D_ * D_) / 8; break;
    default: src = wo; dst = wob; n8 = (D_ * D_) / 8; break;
  }
  int i = blockIdx.x * 256 + threadIdx.x;
  if (i >= n8) return;
  float4 a = ((const float4*)src)[2 * i];
  float4 b = ((const float4*)src)[2 * i + 1];
  short8 o;
  o[0] = (short)f2bf(a.x); o[1] = (short)f2bf(a.y);
  o[2] = (short)f2bf(a.z); o[3] = (short)f2bf(a.w);
  o[4] = (short)f2bf(b.x); o[5] = (short)f2bf(b.y);
  o[6] = (short)f2bf(b.z); o[7] = (short)f2bf(b.w);
  ((short8*)dst)[i] = o;
}

// ---------------------------------------------------------------- QKV projection
// m97 structure, BK=32, N-tile 64 (grid 16,32,3 = 1536 blocks = 6/CU for
// latency overlap). C[m][n] = sum_k A[m][k]*W[n][k].
// z=0: Q (scaled 0.125*log2e) -> [B,H,S,HD]; z=1: K; z=2: V TRANSPOSED -> Vt.
__global__ __launch_bounds__(256) void gemm_qkv(
    const short* __restrict__ xb,  const short* __restrict__ wqb,
    const short* __restrict__ wkb, const short* __restrict__ wvb,
    short* __restrict__ qo, short* __restrict__ ko, short* __restrict__ vto) {
  __shared__ alignas(16) short As[128 * 32];   // 8 KB
  __shared__ alignas(16) short Bs[64 * 32];    // 4 KB
  const int tid  = threadIdx.x;
  const int lane = tid & 63, wid = tid >> 6;
  const int quad = lane >> 4, l16 = lane & 15;
  const int bn = blockIdx.x, bm = blockIdx.y, z = blockIdx.z;
  const short* wsel = (z == 0) ? wqb : ((z == 1) ? wkb : wvb);
  const float scale = (z == 0) ? 0.125f * 1.44269504f : 1.0f;
  const int arow = wid * 32 + (lane >> 2);
  const int acol = (lane & 3) * 8;             // shorts
  const short* ag0 = xb + (bm * 128 + arow) * D_ + acol;
  const short* ag1 = ag0 + 16 * D_;
  const int brow = wid * 16 + (lane >> 2);
  const short* bg0 = wsel + (bn * 64 + brow) * D_ + acol;
  short* la0 = &As[(wid * 32) * 32];
  short* la1 = &As[(wid * 32 + 16) * 32];
  short* lb0 = &Bs[(wid * 16) * 32];
  const int wm = (wid & 1) * 64, wn = (wid >> 1) * 32;
  floatx4 acc[4][2];
#pragma unroll
  for (int i = 0; i < 4; i++)
#pragma unroll
    for (int j = 0; j < 2; j++) acc[i][j] = (floatx4){0.f, 0.f, 0.f, 0.f};

  for (int k0 = 0; k0 < D_; k0 += 32) {
    __syncthreads();
    gl_lds16(ag0 + k0, la0);
    gl_lds16(ag1 + k0, la1);
    gl_lds16(bg0 + k0, lb0);
    __syncthreads();                 // vmcnt(0) drain -> LDS ready
    short8 af[4], bf[2];
#pragma unroll
    for (int t = 0; t < 4; t++) af[t] = *(const short8*)&As[(wm + t * 16 + l16) * 32 + quad * 8];
#pragma unroll
    for (int t = 0; t < 2; t++) bf[t] = *(const short8*)&Bs[(wn + t * 16 + l16) * 32 + quad * 8];
#pragma unroll
    for (int tm = 0; tm < 4; tm++)
#pragma unroll
      for (int tn = 0; tn < 2; tn++)
        acc[tm][tn] = __builtin_amdgcn_mfma_f32_16x16x32_bf16(af[tm], bf[tn], acc[tm][tn], 0, 0, 0);
  }
#pragma unroll
  for (int tm = 0; tm < 4; tm++) {
#pragma unroll
    for (int tn = 0; tn < 2; tn++) {
      int n = bn * 64 + wn + tn * 16 + l16;
      int h = n >> 6, hd = n & 63;
#pragma unroll
      for (int r = 0; r < 4; r++) {
        int m = bm * 128 + wm + tm * 16 + quad * 4 + r;
        int b = m >> 11, s = m & 2047;
        unsigned short val = f2bf(acc[tm][tn][r] * scale);
        if (z == 2)       // Vt [B,H,HD,S]
          vto[((b * H_ + h) * HD_ + hd) * S_ + s] = (short)val;
        else if (z == 1)
          ko[((b * H_ + h) * S_ + s) * HD_ + hd] = (short)val;
        else
          qo[((b * H_ + h) * S_ + s) * HD_ + hd] = (short)val;
      }
    }
  }
}

// ---------------------------------------------------------------- output projection
// N-tile 64: grid (16,32) = 512 blocks = 2/CU (was 1/CU: no overlap at all).
__global__ __launch_bounds__(256) void gemm_out(
    const short* __restrict__ cx, const short* __restrict__ wob,
    const float* __restrict__ bo, float* __restrict__ out) {
  __shared__ alignas(16) short As[128 * 32];
  __shared__ alignas(16) short Bs[64 * 32];
  const int tid  = threadIdx.x;
  const int lane = tid & 63, wid = tid >> 6;
  const int quad = lane >> 4, l16 = lane & 15;
  const int bn = blockIdx.x, bm = blockIdx.y;
  const int arow = wid * 32 + (lane >> 2);
  const int acol = (lane & 3) * 8;
  const short* ag0 = cx + (bm * 128 + arow) * D_ + acol;
  const short* ag1 = ag0 + 16 * D_;
  const int brow = wid * 16 + (lane >> 2);
  const short* bg0 = wob + (bn * 64 + brow) * D_ + acol;
  short* la0 = &As[(wid * 32) * 32];
  short* la1 = &As[(wid * 32 + 16) * 32];
  short* lb0 = &Bs[(wid * 16) * 32];
  const int wm = (wid & 1) * 64, wn = (wid >> 1) * 32;
  floatx4 acc[4][2];
#pragma unroll
  for (int i = 0; i < 4; i++)
#pragma unroll
    for (int j = 0; j < 2; j++) acc[i][j] = (floatx4){0.f, 0.f, 0.f, 0.f};

  for (int k0 = 0; k0 < D_; k0 += 32) {
    __syncthreads();
    gl_lds16(ag0 + k0, la0);
    gl_lds16(ag1 + k0, la1);
    gl_lds16(bg0 + k0, lb0);
    __syncthreads();
    short8 af[4], bf[2];
#pragma unroll
    for (int t = 0; t < 4; t++) af[t] = *(const short8*)&As[(wm + t * 16 + l16) * 32 + quad * 8];
#pragma unroll
    for (int t = 0; t < 2; t++) bf[t] = *(const short8*)&Bs[(wn + t * 16 + l16) * 32 + quad * 8];
#pragma unroll
    for (int tm = 0; tm < 4; tm++)
#pragma unroll
      for (int tn = 0; tn < 2; tn++)
        acc[tm][tn] = __builtin_amdgcn_mfma_f32_16x16x32_bf16(af[tm], bf[tn], acc[tm][tn], 0, 0, 0);
  }
#pragma unroll
  for (int tn = 0; tn < 2; tn++) {
    int n = bn * 64 + wn + tn * 16 + l16;
    float bias = bo[n];
#pragma unroll
    for (int tm = 0; tm < 4; tm++) {
#pragma unroll
      for (int r = 0; r < 4; r++) {
        int m = bm * 128 + wm + tm * 16 + quad * 4 + r;
        out[m * D_ + n] = acc[tm][tn][r] + bias;
      }
    }
  }
}

// ---------------------------------------------------------------- flash attention
// R6 dual-m-set structure (32 Q-rows/wave, K/V frags + barriers amortized over
// 2 m-sets; measured 0.75x per-work cost vs single) + R8's exact per-CU
// balancing. Grid (16,32), blockID->CU = id%256 round-robin => a CU's 2 blocks
// have by, by+16; mapping qtile = ((by>>4)&1) ? bx : 15-bx makes per-CU k-tile
// depth sum uniform (34) for every CU.
// Fixed-rebase softmax p = 2^(y-32), y = score*log2e folded into Q scale.
__global__ __launch_bounds__(256) void attn_kernel(
    const short* __restrict__ qbuf, const short* __restrict__ kbuf,
    const short* __restrict__ vtbuf, short* __restrict__ ctx) {
  __shared__ alignas(16) short Ks[64][72];      // [s][hd]
  __shared__ alignas(16) short Vs[64][72];      // [hd][s]
  __shared__ alignas(16) short Ps[4][32][72];   // per-wave P, 32 rows
  const int tid  = threadIdx.x;
  const int lane = tid & 63, wid = tid >> 6;
  const int quad = lane >> 4, l16 = lane & 15;
  const int bx = blockIdx.x, by = blockIdx.y;
  const int qtile = ((by >> 4) & 1) ? bx : (15 - bx);   // balanced per CU
  const int bh = by;
  const int base = bh * (S_ * HD_);
  const int q0 = qtile * 128 + wid * 32;   // first of this wave's 32 rows

  short8 qf[2][2];
#pragma unroll
  for (int ms = 0; ms < 2; ms++) {
    qf[ms][0] = *(const short8*)(qbuf + base + (q0 + ms * 16 + l16) * HD_ + quad * 8);
    qf[ms][1] = *(const short8*)(qbuf + base + (q0 + ms * 16 + l16) * HD_ + 32 + quad * 8);
  }

  float lsum[2][4];
  floatx4 o[2][4];
#pragma unroll
  for (int ms = 0; ms < 2; ms++)
#pragma unroll
    for (int r = 0; r < 4; r++) { lsum[ms][r] = 0.f; o[ms][r] = (floatx4){0.f, 0.f, 0.f, 0.f}; }

  const int row = tid >> 2, c8 = (tid & 3) * 16;   // staging coords
  const short* kg = kbuf  + base + row * HD_ + c8;
  const short* vg = vtbuf + base + row * S_  + c8;  // row = hd
  short8 kv0 = *(const short8*)(kg);
  short8 kv1 = *(const short8*)(kg + 8);
  short8 vv0 = *(const short8*)(vg);
  short8 vv1 = *(const short8*)(vg + 8);

  const int nkt = 2 * (qtile + 1);
  for (int kt = 0; kt < nkt; kt++) {
    __syncthreads();
    *(short8*)&Ks[row][c8]     = kv0;
    *(short8*)&Ks[row][c8 + 8] = kv1;
    *(short8*)&Vs[row][c8]     = vv0;
    *(short8*)&Vs[row][c8 + 8] = vv1;
    __syncthreads();
    {   // prefetch next tile (clamped; last-iter value unused)
      const int ktn = (kt + 1 < nkt) ? kt + 1 : kt;
      const short* kgn = kg + ktn * 64 * HD_;
      const short* vgn = vg + ktn * 64;
      kv0 = *(const short8*)(kgn);
      kv1 = *(const short8*)(kgn + 8);
      vv0 = *(const short8*)(vgn);
      vv1 = *(const short8*)(vgn + 8);
    }
    if (kt * 64 <= q0 + 31) {     // wave has at least one unmasked row
      floatx4 sc[2][4];
#pragma unroll
      for (int ct = 0; ct < 4; ct++) {
        short8 kb0 = *(const short8*)&Ks[ct * 16 + l16][quad * 8];
        short8 kb1 = *(const short8*)&Ks[ct * 16 + l16][32 + quad * 8];
#pragma unroll
        for (int ms = 0; ms < 2; ms++) {
          floatx4 zz = (floatx4){0.f, 0.f, 0.f, 0.f};
          zz          = __builtin_amdgcn_mfma_f32_16x16x32_bf16(qf[ms][0], kb0, zz, 0, 0, 0);
          sc[ms][ct]  = __builtin_amdgcn_mfma_f32_16x16x32_bf16(qf[ms][1], kb1, zz, 0, 0, 0);
        }
      }
#pragma unroll
      for (int ms = 0; ms < 2; ms++) {
        if (kt * 64 + 63 > q0 + ms * 16) {   // causal mask on boundary tiles
#pragma unroll
          for (int ct = 0; ct < 4; ct++)
#pragma unroll
            for (int r = 0; r < 4; r++)
              if (kt * 64 + ct * 16 + l16 > q0 + ms * 16 + quad * 4 + r)
                sc[ms][ct][r] = -INFINITY;
        }
      }
#pragma unroll
      for (int ms = 0; ms < 2; ms++)
#pragma unroll
        for (int r = 0; r < 4; r++)
#pragma unroll
          for (int ct = 0; ct < 4; ct++) {
            float p = __builtin_amdgcn_exp2f(sc[ms][ct][r] - 32.0f);
            lsum[ms][r] += p;
            Ps[wid][ms * 16 + quad * 4 + r][ct * 16 + l16] = (short)(__float_as_uint(p) >> 16);
          }
#pragma unroll
      for (int ks = 0; ks < 2; ks++) {
        short8 vb[4];
#pragma unroll
        for (int nt = 0; nt < 4; nt++)
          vb[nt] = *(const short8*)&Vs[nt * 16 + l16][ks * 32 + quad * 8];
#pragma unroll
        for (int ms = 0; ms < 2; ms++) {
          short8 pa = *(const short8*)&Ps[wid][ms * 16 + l16][ks * 32 + quad * 8];
#pragma unroll
          for (int nt = 0; nt < 4; nt++)
            o[ms][nt] = __builtin_amdgcn_mfma_f32_16x16x32_bf16(pa, vb[nt], o[ms][nt], 0, 0, 0);
        }
      }
    }
  }
  // epilogue: cross-lane l reduction (within 16-lane groups), then write ctx
#pragma unroll
  for (int ms = 0; ms < 2; ms++)
#pragma unroll
    for (int r = 0; r < 4; r++) {
      float ls = lsum[ms][r];
      ls += __shfl_xor(ls, 1);
      ls += __shfl_xor(ls, 2);
      ls += __shfl_xor(ls, 4);
      ls += __shfl_xor(ls, 8);
      float linv = 1.f / ls;
      int s = q0 + ms * 16 + quad * 4 + r;
      int rowbase = ((bh >> 4) * S_ + s) * D_ + (bh & 15) * HD_;
#pragma unroll
      for (int nt = 0; nt < 4; nt++)
        ctx[rowbase + nt * 16 + l16] = (short)f2bf(o[ms][nt][r] * linv);
    }
}

// ---------------------------------------------------------------- launch
extern "C" void kernel_launch(void* const* d_in, const int* in_sizes, int n_in,
                              void* d_out, int out_size, void* d_ws, size_t ws_size,
                              hipStream_t stream) {
  const float* x  = (const float*)d_in[0];
  const float* wq = (const float*)d_in[1];
  const float* wk = (const float*)d_in[2];
  const float* wv = (const float*)d_in[3];
  const float* wo = (const float*)d_in[4];
  const float* bo = (const float*)d_in[5];
  float* out = (float*)d_out;

  char* ws = (char*)d_ws;
  short* xb  = (short*)(ws);                    // 8 MB
  short* wqb = (short*)(ws + (8u  << 20));      // 2 MB
  short* wkb = (short*)(ws + (10u << 20));      // 2 MB
  short* wvb = (short*)(ws + (12u << 20));      // 2 MB
  short* wob = (short*)(ws + (14u << 20));      // 2 MB
  short* qb  = (short*)(ws + (16u << 20));      // 8 MB  [B,H,S,HD]
  short* kb  = (short*)(ws + (24u << 20));      // 8 MB  [B,H,S,HD]
  short* cx  = (short*)(ws + (32u << 20));      // 8 MB  [M,D]
  short* vtb = (short*)(ws + (40u << 20));      // 8 MB  [B,H,HD,S] -> total 48 MB

  cast_kernel<<<dim3(2048, 5),  256, 0, stream>>>(x, wq, wk, wv, wo, xb, wqb, wkb, wvb, wob);
  gemm_qkv   <<<dim3(16, 32, 3), 256, 0, stream>>>(xb, wqb, wkb, wvb, qb, kb, vtb);
  attn_kernel<<<dim3(16, 32),   256, 0, stream>>>(qb, kb, vtb, cx);
  gemm_out   <<<dim3(16, 32),   256, 0, stream>>>(cx, wob, bo, out);
}

// Round 10
// 197.472 us; speedup vs baseline: 1.0625x; 1.0625x over previous
//
#include <hip/hip_runtime.h>

#define B_  2
#define S_  2048
#define D_  1024
#define H_  16
#define HD_ 64
#define M_  4096   // B_*S_

typedef __attribute__((ext_vector_type(8))) short  short8;
typedef __attribute__((ext_vector_type(4))) float  floatx4;

__device__ __forceinline__ unsigned short f2bf(float f) {
  unsigned int u = __float_as_uint(f);
  u = (u + 0x7fffu + ((u >> 16) & 1u)) >> 16;   // RNE
  return (unsigned short)u;
}

// async global->LDS, 16B per lane; lds dest = wave-uniform base + lane*16
__device__ __forceinline__ void gl_lds16(const short* g, short* l) {
  __builtin_amdgcn_global_load_lds(
      (const __attribute__((address_space(1))) unsigned int*)g,
      (__attribute__((address_space(3))) unsigned int*)l, 16, 0, 0);
}

// ---------------------------------------------------------------- cast fp32->bf16
__global__ __launch_bounds__(256) void cast_kernel(
    const float* __restrict__ x,  const float* __restrict__ wq,
    const float* __restrict__ wk, const float* __restrict__ wv,
    const float* __restrict__ wo,
    short* __restrict__ xb,  short* __restrict__ wqb, short* __restrict__ wkb,
    short* __restrict__ wvb, short* __restrict__ wob) {
  const float* src; short* dst; int n8;
  switch (blockIdx.y) {
    case 0:  src = x;  dst = xb;  n8 = (M_ * D_) / 8; break;
    case 1:  src = wq; dst = wqb; n8 = (D_ * D_) / 8; break;
    case 2:  src = wk; dst = wkb; n8 = (D_ * D_) / 8; break;
    case 3:  src = wv; dst = wvb; n8 = (D_ * D_) / 8; break;
    default: src = wo; dst = wob; n8 = (D_ * D_) / 8; break;
  }
  int i = blockIdx.x * 256 + threadIdx.x;
  if (i >= n8) return;
  float4 a = ((const float4*)src)[2 * i];
  float4 b = ((const float4*)src)[2 * i + 1];
  short8 o;
  o[0] = (short)f2bf(a.x); o[1] = (short)f2bf(a.y);
  o[2] = (short)f2bf(a.z); o[3] = (short)f2bf(a.w);
  o[4] = (short)f2bf(b.x); o[5] = (short)f2bf(b.y);
  o[6] = (short)f2bf(b.z); o[7] = (short)f2bf(b.w);
  ((short8*)dst)[i] = o;
}

// ---------------------------------------------------------------- QKV projection
// R8-proven: m97 structure, BK=32, 128x128 tile (N-64 regressed in R9 —
// staging:MFMA ratio dominates occupancy; matches m103/m112 tile sweep).
// z=0: Q (scaled 0.125*log2e) -> [B,H,S,HD]; z=1: K; z=2: V TRANSPOSED -> Vt.
__global__ __launch_bounds__(256) void gemm_qkv(
    const short* __restrict__ xb,  const short* __restrict__ wqb,
    const short* __restrict__ wkb, const short* __restrict__ wvb,
    short* __restrict__ qo, short* __restrict__ ko, short* __restrict__ vto) {
  __shared__ alignas(16) short As[128 * 32];   // row-major, 64B/row
  __shared__ alignas(16) short Bs[128 * 32];
  const int tid  = threadIdx.x;
  const int lane = tid & 63, wid = tid >> 6;
  const int quad = lane >> 4, l16 = lane & 15;
  const int bn = blockIdx.x, bm = blockIdx.y, z = blockIdx.z;
  const short* wsel = (z == 0) ? wqb : ((z == 1) ? wkb : wvb);
  const float scale = (z == 0) ? 0.125f * 1.44269504f : 1.0f;
  const int lrow = wid * 32 + (lane >> 2);
  const int lcol = (lane & 3) * 8;             // shorts
  const short* ag0 = xb   + (bm * 128 + lrow) * D_ + lcol;
  const short* ag1 = ag0 + 16 * D_;
  const short* bg0 = wsel + (bn * 128 + lrow) * D_ + lcol;
  const short* bg1 = bg0 + 16 * D_;
  short* la0 = &As[(wid * 32) * 32];
  short* la1 = &As[(wid * 32 + 16) * 32];
  short* lb0 = &Bs[(wid * 32) * 32];
  short* lb1 = &Bs[(wid * 32 + 16) * 32];
  const int wm = (wid & 1) * 64, wn = (wid >> 1) * 64;
  floatx4 acc[4][4];
#pragma unroll
  for (int i = 0; i < 4; i++)
#pragma unroll
    for (int j = 0; j < 4; j++) acc[i][j] = (floatx4){0.f, 0.f, 0.f, 0.f};

  for (int k0 = 0; k0 < D_; k0 += 32) {
    __syncthreads();
    gl_lds16(ag0 + k0, la0);
    gl_lds16(ag1 + k0, la1);
    gl_lds16(bg0 + k0, lb0);
    gl_lds16(bg1 + k0, lb1);
    __syncthreads();                 // vmcnt(0) drain -> LDS ready
    short8 af[4], bf[4];
#pragma unroll
    for (int t = 0; t < 4; t++) af[t] = *(const short8*)&As[(wm + t * 16 + l16) * 32 + quad * 8];
#pragma unroll
    for (int t = 0; t < 4; t++) bf[t] = *(const short8*)&Bs[(wn + t * 16 + l16) * 32 + quad * 8];
#pragma unroll
    for (int tm = 0; tm < 4; tm++)
#pragma unroll
      for (int tn = 0; tn < 4; tn++)
        acc[tm][tn] = __builtin_amdgcn_mfma_f32_16x16x32_bf16(af[tm], bf[tn], acc[tm][tn], 0, 0, 0);
  }
#pragma unroll
  for (int tm = 0; tm < 4; tm++) {
#pragma unroll
    for (int tn = 0; tn < 4; tn++) {
      int n = bn * 128 + wn + tn * 16 + l16;
      int h = n >> 6, hd = n & 63;
#pragma unroll
      for (int r = 0; r < 4; r++) {
        int m = bm * 128 + wm + tm * 16 + quad * 4 + r;
        int b = m >> 11, s = m & 2047;
        unsigned short val = f2bf(acc[tm][tn][r] * scale);
        if (z == 2)       // Vt [B,H,HD,S]
          vto[((b * H_ + h) * HD_ + hd) * S_ + s] = (short)val;
        else if (z == 1)
          ko[((b * H_ + h) * S_ + s) * HD_ + hd] = (short)val;
        else
          qo[((b * H_ + h) * S_ + s) * HD_ + hd] = (short)val;
      }
    }
  }
}

// ---------------------------------------------------------------- output projection
// R8-proven 128x128/BK=32.
__global__ __launch_bounds__(256) void gemm_out(
    const short* __restrict__ cx, const short* __restrict__ wob,
    const float* __restrict__ bo, float* __restrict__ out) {
  __shared__ alignas(16) short As[128 * 32];
  __shared__ alignas(16) short Bs[128 * 32];
  const int tid  = threadIdx.x;
  const int lane = tid & 63, wid = tid >> 6;
  const int quad = lane >> 4, l16 = lane & 15;
  const int bn = blockIdx.x, bm = blockIdx.y;
  const int lrow = wid * 32 + (lane >> 2);
  const int lcol = (lane & 3) * 8;
  const short* ag0 = cx  + (bm * 128 + lrow) * D_ + lcol;
  const short* ag1 = ag0 + 16 * D_;
  const short* bg0 = wob + (bn * 128 + lrow) * D_ + lcol;
  const short* bg1 = bg0 + 16 * D_;
  short* la0 = &As[(wid * 32) * 32];
  short* la1 = &As[(wid * 32 + 16) * 32];
  short* lb0 = &Bs[(wid * 32) * 32];
  short* lb1 = &Bs[(wid * 32 + 16) * 32];
  const int wm = (wid & 1) * 64, wn = (wid >> 1) * 64;
  floatx4 acc[4][4];
#pragma unroll
  for (int i = 0; i < 4; i++)
#pragma unroll
    for (int j = 0; j < 4; j++) acc[i][j] = (floatx4){0.f, 0.f, 0.f, 0.f};

  for (int k0 = 0; k0 < D_; k0 += 32) {
    __syncthreads();
    gl_lds16(ag0 + k0, la0);
    gl_lds16(ag1 + k0, la1);
    gl_lds16(bg0 + k0, lb0);
    gl_lds16(bg1 + k0, lb1);
    __syncthreads();
    short8 af[4], bf[4];
#pragma unroll
    for (int t = 0; t < 4; t++) af[t] = *(const short8*)&As[(wm + t * 16 + l16) * 32 + quad * 8];
#pragma unroll
    for (int t = 0; t < 4; t++) bf[t] = *(const short8*)&Bs[(wn + t * 16 + l16) * 32 + quad * 8];
#pragma unroll
    for (int tm = 0; tm < 4; tm++)
#pragma unroll
      for (int tn = 0; tn < 4; tn++)
        acc[tm][tn] = __builtin_amdgcn_mfma_f32_16x16x32_bf16(af[tm], bf[tn], acc[tm][tn], 0, 0, 0);
  }
#pragma unroll
  for (int tn = 0; tn < 4; tn++) {
    int n = bn * 128 + wn + tn * 16 + l16;
    float bias = bo[n];
#pragma unroll
    for (int tm = 0; tm < 4; tm++) {
#pragma unroll
      for (int r = 0; r < 4; r++) {
        int m = bm * 128 + wm + tm * 16 + quad * 4 + r;
        out[m * D_ + n] = acc[tm][tn][r] + bias;
      }
    }
  }
}

// ---------------------------------------------------------------- flash attention
// R9 kernel (kept): dual-m-set (32 Q-rows/wave) + exact per-CU balancing.
// Grid (16,32); blockID->CU = id%256 => CU's 2 blocks have by, by+16;
// qtile = ((by>>4)&1) ? bx : 15-bx -> uniform 34-slot depth per CU.
// Fixed-rebase softmax p = 2^(y-32), y = score*log2e folded into Q scale.
__global__ __launch_bounds__(256) void attn_kernel(
    const short* __restrict__ qbuf, const short* __restrict__ kbuf,
    const short* __restrict__ vtbuf, short* __restrict__ ctx) {
  __shared__ alignas(16) short Ks[64][72];      // [s][hd]
  __shared__ alignas(16) short Vs[64][72];      // [hd][s]
  __shared__ alignas(16) short Ps[4][32][72];   // per-wave P, 32 rows
  const int tid  = threadIdx.x;
  const int lane = tid & 63, wid = tid >> 6;
  const int quad = lane >> 4, l16 = lane & 15;
  const int bx = blockIdx.x, by = blockIdx.y;
  const int qtile = ((by >> 4) & 1) ? bx : (15 - bx);   // balanced per CU
  const int bh = by;
  const int base = bh * (S_ * HD_);
  const int q0 = qtile * 128 + wid * 32;   // first of this wave's 32 rows

  short8 qf[2][2];
#pragma unroll
  for (int ms = 0; ms < 2; ms++) {
    qf[ms][0] = *(const short8*)(qbuf + base + (q0 + ms * 16 + l16) * HD_ + quad * 8);
    qf[ms][1] = *(const short8*)(qbuf + base + (q0 + ms * 16 + l16) * HD_ + 32 + quad * 8);
  }

  float lsum[2][4];
  floatx4 o[2][4];
#pragma unroll
  for (int ms = 0; ms < 2; ms++)
#pragma unroll
    for (int r = 0; r < 4; r++) { lsum[ms][r] = 0.f; o[ms][r] = (floatx4){0.f, 0.f, 0.f, 0.f}; }

  const int row = tid >> 2, c8 = (tid & 3) * 16;   // staging coords
  const short* kg = kbuf  + base + row * HD_ + c8;
  const short* vg = vtbuf + base + row * S_  + c8;  // row = hd
  short8 kv0 = *(const short8*)(kg);
  short8 kv1 = *(const short8*)(kg + 8);
  short8 vv0 = *(const short8*)(vg);
  short8 vv1 = *(const short8*)(vg + 8);

  const int nkt = 2 * (qtile + 1);
  for (int kt = 0; kt < nkt; kt++) {
    __syncthreads();
    *(short8*)&Ks[row][c8]     = kv0;
    *(short8*)&Ks[row][c8 + 8] = kv1;
    *(short8*)&Vs[row][c8]     = vv0;
    *(short8*)&Vs[row][c8 + 8] = vv1;
    __syncthreads();
    {   // prefetch next tile (clamped; last-iter value unused)
      const int ktn = (kt + 1 < nkt) ? kt + 1 : kt;
      const short* kgn = kg + ktn * 64 * HD_;
      const short* vgn = vg + ktn * 64;
      kv0 = *(const short8*)(kgn);
      kv1 = *(const short8*)(kgn + 8);
      vv0 = *(const short8*)(vgn);
      vv1 = *(const short8*)(vgn + 8);
    }
    if (kt * 64 <= q0 + 31) {     // wave has at least one unmasked row
      floatx4 sc[2][4];
#pragma unroll
      for (int ct = 0; ct < 4; ct++) {
        short8 kb0 = *(const short8*)&Ks[ct * 16 + l16][quad * 8];
        short8 kb1 = *(const short8*)&Ks[ct * 16 + l16][32 + quad * 8];
#pragma unroll
        for (int ms = 0; ms < 2; ms++) {
          floatx4 zz = (floatx4){0.f, 0.f, 0.f, 0.f};
          zz          = __builtin_amdgcn_mfma_f32_16x16x32_bf16(qf[ms][0], kb0, zz, 0, 0, 0);
          sc[ms][ct]  = __builtin_amdgcn_mfma_f32_16x16x32_bf16(qf[ms][1], kb1, zz, 0, 0, 0);
        }
      }
#pragma unroll
      for (int ms = 0; ms < 2; ms++) {
        if (kt * 64 + 63 > q0 + ms * 16) {   // causal mask on boundary tiles
#pragma unroll
          for (int ct = 0; ct < 4; ct++)
#pragma unroll
            for (int r = 0; r < 4; r++)
              if (kt * 64 + ct * 16 + l16 > q0 + ms * 16 + quad * 4 + r)
                sc[ms][ct][r] = -INFINITY;
        }
      }
#pragma unroll
      for (int ms = 0; ms < 2; ms++)
#pragma unroll
        for (int r = 0; r < 4; r++)
#pragma unroll
          for (int ct = 0; ct < 4; ct++) {
            float p = __builtin_amdgcn_exp2f(sc[ms][ct][r] - 32.0f);
            lsum[ms][r] += p;
            Ps[wid][ms * 16 + quad * 4 + r][ct * 16 + l16] = (short)(__float_as_uint(p) >> 16);
          }
#pragma unroll
      for (int ks = 0; ks < 2; ks++) {
        short8 vb[4];
#pragma unroll
        for (int nt = 0; nt < 4; nt++)
          vb[nt] = *(const short8*)&Vs[nt * 16 + l16][ks * 32 + quad * 8];
#pragma unroll
        for (int ms = 0; ms < 2; ms++) {
          short8 pa = *(const short8*)&Ps[wid][ms * 16 + l16][ks * 32 + quad * 8];
#pragma unroll
          for (int nt = 0; nt < 4; nt++)
            o[ms][nt] = __builtin_amdgcn_mfma_f32_16x16x32_bf16(pa, vb[nt], o[ms][nt], 0, 0, 0);
        }
      }
    }
  }
  // epilogue: cross-lane l reduction (within 16-lane groups), then write ctx
#pragma unroll
  for (int ms = 0; ms < 2; ms++)
#pragma unroll
    for (int r = 0; r < 4; r++) {
      float ls = lsum[ms][r];
      ls += __shfl_xor(ls, 1);
      ls += __shfl_xor(ls, 2);
      ls += __shfl_xor(ls, 4);
      ls += __shfl_xor(ls, 8);
      float linv = 1.f / ls;
      int s = q0 + ms * 16 + quad * 4 + r;
      int rowbase = ((bh >> 4) * S_ + s) * D_ + (bh & 15) * HD_;
#pragma unroll
      for (int nt = 0; nt < 4; nt++)
        ctx[rowbase + nt * 16 + l16] = (short)f2bf(o[ms][nt][r] * linv);
    }
}

// ---------------------------------------------------------------- launch
extern "C" void kernel_launch(void* const* d_in, const int* in_sizes, int n_in,
                              void* d_out, int out_size, void* d_ws, size_t ws_size,
                              hipStream_t stream) {
  const float* x  = (const float*)d_in[0];
  const float* wq = (const float*)d_in[1];
  const float* wk = (const float*)d_in[2];
  const float* wv = (const float*)d_in[3];
  const float* wo = (const float*)d_in[4];
  const float* bo = (const float*)d_in[5];
  float* out = (float*)d_out;

  char* ws = (char*)d_ws;
  short* xb  = (short*)(ws);                    // 8 MB
  short* wqb = (short*)(ws + (8u  << 20));      // 2 MB
  short* wkb = (short*)(ws + (10u << 20));      // 2 MB
  short* wvb = (short*)(ws + (12u << 20));      // 2 MB
  short* wob = (short*)(ws + (14u << 20));      // 2 MB
  short* qb  = (short*)(ws + (16u << 20));      // 8 MB  [B,H,S,HD]
  short* kb  = (short*)(ws + (24u << 20));      // 8 MB  [B,H,S,HD]
  short* cx  = (short*)(ws + (32u << 20));      // 8 MB  [M,D]
  short* vtb = (short*)(ws + (40u << 20));      // 8 MB  [B,H,HD,S] -> total 48 MB

  cast_kernel<<<dim3(2048, 5),  256, 0, stream>>>(x, wq, wk, wv, wo, xb, wqb, wkb, wvb, wob);
  gemm_qkv   <<<dim3(8, 32, 3), 256, 0, stream>>>(xb, wqb, wkb, wvb, qb, kb, vtb);
  attn_kernel<<<dim3(16, 32),   256, 0, stream>>>(qb, kb, vtb, cx);
  gemm_out   <<<dim3(8, 32),    256, 0, stream>>>(cx, wob, bo, out);
}